// Round 2
// 2614.404 us; speedup vs baseline: 1.2168x; 1.2168x over previous
//
#include <hip/hip_runtime.h>
#include <hip/hip_bf16.h>
#include <math.h>

// GRU encoder: B=512, T=128, V=128, E=512, H=512, L=2
// Round 4 (= Round 3 hardened): persistent cooperative kernel.
//  - gi0_table[v][3H] = emb[v]@Wi0^T + b_ih0 precomputed in f32 (V=128!)
//  - one persistent kernel, 192 blocks x 512 thr, hand-rolled grid barrier.
//  - superstep s: blocks 0..63 compute layer0@t=s (K=512, h@Wh0^T),
//    blocks 64..191 compute layer1@t=s-1 (K=1024, [h0|h1]@[Wi1|Wh1]^T).
//  - LDS staging via global_load_lds(16B), XOR-swizzled SOURCE (linear LDS
//    dest, rule #21) + swizzled ds_read_b128 fragment reads.
//  - f32 h carried in registers; bf16 shadow ping-pongs in ws.
//  - HARDENED: barrier flag memset covers abort word (512B, was 256B bug);
//    spinners poll the abort flag every iteration -> worst case is a fast
//    wrong answer, never a hang.

#define BB 512
#define TT 128
#define VV 128
#define EE 512
#define HH 512
#define LL 2
#define BH (BB*HH)

#define NBLK 192

typedef short s16x8 __attribute__((ext_vector_type(8)));
typedef float f32x4 __attribute__((ext_vector_type(4)));

typedef const __attribute__((address_space(1))) unsigned int* gptr_t;
typedef __attribute__((address_space(3))) unsigned int* lptr_t;

// ---- ws layout ----
#define W_SZ    (3*HH*EE)                         // 786432 bf16 per matrix
#define WH0_OFF 0
#define WI1_OFF (W_SZ)
#define WH1_OFF (2*W_SZ)
#define HBF_OFF (3*W_SZ)
#define HBF_SZ  (4*BH)                            // [L][2][B][H] ping-pong
#define TBL_BYTE ((size_t)(3*W_SZ + HBF_SZ)*2)    // 6815744
#define TBL_SZ   (VV*3*HH)                        // 196608 f32
#define BAR_BYTE (TBL_BYTE + (size_t)TBL_SZ*4)    // 7602176; total ~7.6MB

#define MFMA(a,b,c) __builtin_amdgcn_mfma_f32_16x16x32_bf16((a),(b),(c),0,0,0)

__global__ __launch_bounds__(256) void f32_to_bf16(
    const float* __restrict__ src, __hip_bfloat16* __restrict__ dst, int n)
{
    int i = blockIdx.x * 256 + threadIdx.x;
    if (i < n) dst[i] = __float2bfloat16(src[i]);
}

// gi0_table[v][col] = dot(emb[v], w_ih0[col]) + b_ih0[col]   (full f32)
__global__ __launch_bounds__(256) void build_gi0(
    const float* __restrict__ emb, const float* __restrict__ w_ih,
    const float* __restrict__ b_ih, float* __restrict__ tbl)
{
    __shared__ __align__(16) float e[EE];
    const int v   = blockIdx.y;
    const int col = blockIdx.x * 256 + threadIdx.x;   // 0..1535
    for (int i = threadIdx.x; i < EE; i += 256) e[i] = emb[v * EE + i];
    __syncthreads();
    const float4* w4 = (const float4*)(w_ih + (size_t)col * EE);
    const float4* e4 = (const float4*)e;
    float acc = 0.f;
    #pragma unroll 8
    for (int k = 0; k < EE/4; ++k) {
        float4 wv = w4[k], ev = e4[k];
        acc += wv.x*ev.x + wv.y*ev.y + wv.z*ev.z + wv.w*ev.w;
    }
    tbl[v * (3*HH) + col] = acc + b_ih[col];
}

__device__ __forceinline__ void gl_lds16(const void* g, void* l) {
    __builtin_amdgcn_global_load_lds((gptr_t)g, (lptr_t)l, 16, 0, 0);
}

// swizzled fragment read: tile row-major [rows][128] bf16, 16B block kb,
// stored at kb ^ (row&7); conflict-free ds_read_b128.
__device__ __forceinline__ s16x8 frag_ld(const __hip_bfloat16* tb, int row, int kb) {
    const char* p = (const char*)tb + row * 256 + (((kb ^ (row & 7)) & 15) << 4);
    return *(const s16x8*)p;
}

__device__ __forceinline__ float sigm(float x) { return 1.f / (1.f + __expf(-x)); }
__device__ __forceinline__ float tanh_f(float x) {
    float e2 = __expf(2.f * x);
    return 1.f - 2.f / (e2 + 1.f);     // safe at +/-inf of e2
}

// device-scope grid barrier: bar[0]=count, bar[32]=gen, bar[64]=abort
// Anti-hang: spinners poll abort every iteration; timeout sets abort.
// Worst case = wrong answer (test fails), never a wedged GPU.
__device__ __forceinline__ void grid_sync(unsigned* bar) {
    __syncthreads();
    if (threadIdx.x == 0) {
        unsigned* cnt = bar;
        unsigned* gen = bar + 32;
        unsigned* abt = bar + 64;
        if (__hip_atomic_load(abt, __ATOMIC_RELAXED, __HIP_MEMORY_SCOPE_AGENT) == 0u) {
            unsigned g = __hip_atomic_load(gen, __ATOMIC_RELAXED, __HIP_MEMORY_SCOPE_AGENT);
            unsigned a = __hip_atomic_fetch_add(cnt, 1u, __ATOMIC_RELEASE, __HIP_MEMORY_SCOPE_AGENT);
            if (a == (unsigned)(NBLK - 1)) {
                __hip_atomic_store(cnt, 0u, __ATOMIC_RELAXED, __HIP_MEMORY_SCOPE_AGENT);
                __hip_atomic_store(gen, g + 1u, __ATOMIC_RELEASE, __HIP_MEMORY_SCOPE_AGENT);
            } else {
                int spins = 0;
                while (__hip_atomic_load(gen, __ATOMIC_RELAXED, __HIP_MEMORY_SCOPE_AGENT) == g) {
                    if (__hip_atomic_load(abt, __ATOMIC_RELAXED, __HIP_MEMORY_SCOPE_AGENT) != 0u)
                        break;
                    __builtin_amdgcn_s_sleep(2);
                    if (++spins > (1 << 20)) {   // ~50ms: poison & bail
                        __hip_atomic_store(abt, 1u, __ATOMIC_RELAXED, __HIP_MEMORY_SCOPE_AGENT);
                        break;
                    }
                }
            }
        }
        __threadfence();   // acquire: invalidate stale L1/L2 lines
    }
    __syncthreads();
}

__global__ __launch_bounds__(512) void gru_persist(
    const int*   __restrict__ input,   // [B,T]
    const float* __restrict__ h0,      // [L,B,H] f32
    const float* __restrict__ b_ih,    // [L,3H]
    const float* __restrict__ b_hh,    // [L,3H]
    const __hip_bfloat16* __restrict__ wh0,  // [3H,512]
    const __hip_bfloat16* __restrict__ wi1,  // [3H,512]
    const __hip_bfloat16* __restrict__ wh1,  // [3H,512]
    const float* __restrict__ tbl,           // [V,3H]
    __hip_bfloat16* __restrict__ hbf,        // [L][2][B][H]
    float*       __restrict__ out,           // [T,L,B,H]
    unsigned*    __restrict__ bar)
{
    __shared__ __align__(16) __hip_bfloat16 smem[32768];  // 64KB: A[64][128] + B[192][128]
    __hip_bfloat16* As = smem;
    __hip_bfloat16* Bs = smem + 8192;

    const int tid  = threadIdx.x;
    const int w    = tid >> 6;
    const int lane = tid & 63;
    const int l15  = lane & 15;
    const int lg   = lane >> 4;
    const int bid  = blockIdx.x;

    if (bid < 64) {
        // ================= layer 0: h@Wh0^T, K=512 =================
        const int bt = bid >> 3, ht = bid & 7;   // batch-64 tile, h-64 tile
        const int wq = w >> 2,  hq = w & 3;      // wave: 32-batch half, 16-h quarter

        int aoff[2], boff[6];
        #pragma unroll
        for (int i = 0; i < 2; ++i) {
            int ra = w*8 + i*4 + lg;                          // A tile row 0..63
            aoff[i] = (bt*64 + ra)*HH + ((l15 ^ (ra & 7)) << 3);
        }
        #pragma unroll
        for (int i = 0; i < 6; ++i) {
            int rb = w*24 + i*4 + lg;                         // B tile row 0..191
            int gg = rb >> 6, hc = rb & 63;
            boff[i] = (gg*HH + ht*64 + hc)*HH + ((l15 ^ (rb & 7)) << 3);
        }
        const int arow0 = wq*32 + l15, arow1 = wq*32 + 16 + l15;
        const int brow0 = hq*16 + l15, brow1 = 64 + hq*16 + l15, brow2 = 128 + hq*16 + l15;

        const int hcol = ht*64 + hq*16 + l15;
        const float bhr = b_hh[hcol], bhz = b_hh[512 + hcol], bhn = b_hh[1024 + hcol];

        float hreg[2][4];
        #pragma unroll
        for (int s2 = 0; s2 < 2; ++s2)
            #pragma unroll
            for (int r = 0; r < 4; ++r) {
                int b = bt*64 + wq*32 + s2*16 + lg*4 + r;
                hreg[s2][r] = h0[(size_t)b*HH + hcol];
            }

        for (int t = 0; t < TT; ++t) {
            const __hip_bfloat16* Asrc = hbf + (size_t)((t + 1) & 1) * BH;  // h0[t-1]
            f32x4 acc[2][3];
            #pragma unroll
            for (int s2 = 0; s2 < 2; ++s2)
                #pragma unroll
                for (int g2 = 0; g2 < 3; ++g2) acc[s2][g2] = (f32x4)(0.f);

            #pragma unroll
            for (int c = 0; c < 4; ++c) {
                const int kc = c * 128;
                #pragma unroll
                for (int i = 0; i < 2; ++i)
                    gl_lds16(Asrc + aoff[i] + kc, As + (w*8 + i*4)*128);
                #pragma unroll
                for (int i = 0; i < 6; ++i)
                    gl_lds16(wh0 + boff[i] + kc, Bs + (w*24 + i*4)*128);
                __syncthreads();
                #pragma unroll
                for (int ks = 0; ks < 4; ++ks) {
                    const int kb = ks*4 + lg;
                    s16x8 a0 = frag_ld(As, arow0, kb);
                    s16x8 a1 = frag_ld(As, arow1, kb);
                    s16x8 b0 = frag_ld(Bs, brow0, kb);
                    s16x8 b1 = frag_ld(Bs, brow1, kb);
                    s16x8 b2 = frag_ld(Bs, brow2, kb);
                    acc[0][0] = MFMA(a0, b0, acc[0][0]);  acc[1][0] = MFMA(a1, b0, acc[1][0]);
                    acc[0][1] = MFMA(a0, b1, acc[0][1]);  acc[1][1] = MFMA(a1, b1, acc[1][1]);
                    acc[0][2] = MFMA(a0, b2, acc[0][2]);  acc[1][2] = MFMA(a1, b2, acc[1][2]);
                }
                __syncthreads();
            }

            float* outp = out + (size_t)(t * 2) * BH;
            __hip_bfloat16* hw = hbf + (size_t)(t & 1) * BH;
            #pragma unroll
            for (int s2 = 0; s2 < 2; ++s2)
                #pragma unroll
                for (int r = 0; r < 4; ++r) {
                    int b = bt*64 + wq*32 + s2*16 + lg*4 + r;
                    int v = input[b*TT + t];
                    const float* tv = tbl + v*(3*HH) + hcol;
                    float rg = sigm(acc[s2][0][r] + tv[0]   + bhr);
                    float zg = sigm(acc[s2][1][r] + tv[512] + bhz);
                    float ng = tanh_f(tv[1024] + rg*(acc[s2][2][r] + bhn));
                    float hn = (1.f - zg)*ng + zg*hreg[s2][r];
                    hreg[s2][r] = hn;
                    outp[(size_t)b*HH + hcol] = hn;
                    hw[(size_t)b*HH + hcol] = __float2bfloat16(hn);
                }
            grid_sync(bar);
        }
    } else {
        // ================= layer 1: [h0|h1]@[Wi1|Wh1]^T, K=1024 =================
        const int id = bid - 64;
        const int bt = id >> 4, ht = id & 15;    // batch-64 tile, h-32 tile
        const int bq = w >> 1,  hq = w & 1;      // wave: 16-batch quarter, 16-h half

        int aoff[2], boff[3];
        #pragma unroll
        for (int i = 0; i < 2; ++i) {
            int ra = w*8 + i*4 + lg;                          // A tile row 0..63
            aoff[i] = (bt*64 + ra)*HH + ((l15 ^ (ra & 7)) << 3);
        }
        #pragma unroll
        for (int i = 0; i < 3; ++i) {
            int rb = w*12 + i*4 + lg;                         // B tile row 0..95
            int gg = rb >> 5, hc = rb & 31;
            boff[i] = (gg*HH + ht*32 + hc)*HH + ((l15 ^ (rb & 7)) << 3);
        }
        const int arow  = bq*16 + l15;
        const int brow0 = hq*16 + l15, brow1 = 32 + hq*16 + l15, brow2 = 64 + hq*16 + l15;

        const int hcol = ht*32 + hq*16 + l15;
        const float bir = b_ih[1536 + hcol], biz = b_ih[1536 + 512 + hcol], bin = b_ih[1536 + 1024 + hcol];
        const float bhr = b_hh[1536 + hcol], bhz = b_hh[1536 + 512 + hcol], bhn = b_hh[1536 + 1024 + hcol];

        float hreg[4];
        #pragma unroll
        for (int r = 0; r < 4; ++r) {
            int b = bt*64 + bq*16 + lg*4 + r;
            hreg[r] = h0[(size_t)BH + (size_t)b*HH + hcol];
        }

        grid_sync(bar);   // barrier 0: wait for layer0@t=0
        for (int t = 0; t < TT; ++t) {
            const __hip_bfloat16* Ax = hbf + (size_t)(t & 1) * BH;            // h0[t]
            const __hip_bfloat16* Ah = hbf + (size_t)(2 + ((t + 1) & 1)) * BH; // h1[t-1]
            f32x4 ar = (f32x4)(0.f), az = (f32x4)(0.f), ani = (f32x4)(0.f), anh = (f32x4)(0.f);

            #pragma unroll
            for (int c = 0; c < 8; ++c) {
                const __hip_bfloat16* Asrc = (c < 4) ? Ax  : Ah;
                const __hip_bfloat16* Bsrc = (c < 4) ? wi1 : wh1;
                const int kc = (c & 3) * 128;
                #pragma unroll
                for (int i = 0; i < 2; ++i)
                    gl_lds16(Asrc + aoff[i] + kc, As + (w*8 + i*4)*128);
                #pragma unroll
                for (int i = 0; i < 3; ++i)
                    gl_lds16(Bsrc + boff[i] + kc, Bs + (w*12 + i*4)*128);
                __syncthreads();
                #pragma unroll
                for (int ks = 0; ks < 4; ++ks) {
                    const int kb = ks*4 + lg;
                    s16x8 a  = frag_ld(As, arow,  kb);
                    s16x8 b0 = frag_ld(Bs, brow0, kb);
                    s16x8 b1 = frag_ld(Bs, brow1, kb);
                    s16x8 b2 = frag_ld(Bs, brow2, kb);
                    ar = MFMA(a, b0, ar);
                    az = MFMA(a, b1, az);
                    if (c < 4) ani = MFMA(a, b2, ani);
                    else       anh = MFMA(a, b2, anh);
                }
                __syncthreads();
            }

            float* outp = out + (size_t)(t * 2 + 1) * BH;
            __hip_bfloat16* hw = hbf + (size_t)(2 + (t & 1)) * BH;
            #pragma unroll
            for (int r = 0; r < 4; ++r) {
                float rg = sigm(ar[r] + bir + bhr);
                float zg = sigm(az[r] + biz + bhz);
                float ng = tanh_f(ani[r] + bin + rg*(anh[r] + bhn));
                float hn = (1.f - zg)*ng + zg*hreg[r];
                hreg[r] = hn;
                int b = bt*64 + bq*16 + lg*4 + r;
                outp[(size_t)b*HH + hcol] = hn;
                hw[(size_t)b*HH + hcol] = __float2bfloat16(hn);
            }
            if (t < TT - 1) grid_sync(bar);
        }
    }
}

__global__ __launch_bounds__(256) void copy_final(
    const float* __restrict__ states, float* __restrict__ dst)
{
    const int i = blockIdx.x * 256 + threadIdx.x;   // L*B*H
    dst[i] = states[(size_t)(TT - 1) * LL * BH + i];
}

extern "C" void kernel_launch(void* const* d_in, const int* in_sizes, int n_in,
                              void* d_out, int out_size, void* d_ws, size_t ws_size,
                              hipStream_t stream) {
    const int*   input = (const int*)  d_in[0];
    const float* h0    = (const float*)d_in[1];
    const float* emb   = (const float*)d_in[2];
    const float* w_ih  = (const float*)d_in[3];
    const float* w_hh  = (const float*)d_in[4];
    const float* b_ih  = (const float*)d_in[5];
    const float* b_hh  = (const float*)d_in[6];
    float* out = (float*)d_out;

    __hip_bfloat16* wsb = (__hip_bfloat16*)d_ws;
    __hip_bfloat16* wh0 = wsb + WH0_OFF;
    __hip_bfloat16* wi1 = wsb + WI1_OFF;
    __hip_bfloat16* wh1 = wsb + WH1_OFF;
    __hip_bfloat16* hbf = wsb + HBF_OFF;
    float*    tbl = (float*)   ((char*)d_ws + TBL_BYTE);
    unsigned* bar = (unsigned*)((char*)d_ws + BAR_BYTE);

    hipMemsetAsync(bar, 0, 512, stream);   // covers cnt(0), gen(128B), abort(256B)
    f32_to_bf16<<<(W_SZ + 255)/256, 256, 0, stream>>>(w_hh,        wh0, W_SZ);
    f32_to_bf16<<<(W_SZ + 255)/256, 256, 0, stream>>>(w_ih + W_SZ, wi1, W_SZ);
    f32_to_bf16<<<(W_SZ + 255)/256, 256, 0, stream>>>(w_hh + W_SZ, wh1, W_SZ);
    // h0 -> bf16 read-slot 1 for t=0, per layer
    f32_to_bf16<<<(BH + 255)/256, 256, 0, stream>>>(h0,      hbf + 1*(size_t)BH, BH);
    f32_to_bf16<<<(BH + 255)/256, 256, 0, stream>>>(h0 + BH, hbf + 3*(size_t)BH, BH);
    build_gi0<<<dim3(6, VV), 256, 0, stream>>>(emb, w_ih, b_ih, tbl);

    gru_persist<<<NBLK, 512, 0, stream>>>(input, h0, b_ih, b_hh,
                                          wh0, wi1, wh1, tbl, hbf, out, bar);

    copy_final<<<(LL*BH)/256, 256, 0, stream>>>(out, out + (size_t)TT * LL * BH);
}